// Round 7
// baseline (398.174 us; speedup 1.0000x reference)
//
#include <hip/hip_runtime.h>
#include <hip/hip_fp16.h>
#include <cstdint>
#include <cstddef>

#define INF_  128
#define OUTF  64
#define ALPHA 0.2f
#define LN_EPS 1e-5f

#define NB    1024        // coarse buckets (src >> 7)
#define LOCB  7           // 128 local nodes per bucket
#define NBLK  512         // edge-partition blocks for count/scatter passes

// ---------------- GEMM: h(fp16) = x @ W^T + b, sl = h@a_l, sr = h@a_r ----------------
__global__ __launch_bounds__(256) void gemm_kernel(
    const float* __restrict__ x, const float* __restrict__ W,
    const float* __restrict__ b, const float* __restrict__ a,
    __half* __restrict__ hh, float* __restrict__ sl, float* __restrict__ sr, int n)
{
    __shared__ float4 Wq[32][64];          // Wq[kq][o]: lane-stride 16B, conflict-free
    __shared__ float4 xs[4][8][32];

    const int tid  = threadIdx.x;
    const int lane = tid & 63;
    const int wv   = tid >> 6;

    for (int idx = tid; idx < 2048; idx += 256) {
        int kq = idx >> 6, o = idx & 63;
        Wq[kq][o] = ((const float4*)W)[o * 32 + kq];
    }
    __syncthreads();

    const float bb = b[lane];
    const float al = a[lane];
    const float ar = a[OUTF + lane];

    const int ngroups = (n + 31) >> 5;
    for (int g = blockIdx.x; g < ngroups; g += gridDim.x) {
        const int node0 = g * 32 + wv * 8;
        for (int t = lane; t < 8 * 32; t += 64) {
            int r = t >> 5, q = t & 31;
            int nd = node0 + r; if (nd >= n) nd = 0;
            xs[wv][r][q] = ((const float4*)x)[(size_t)nd * 32 + q];
        }
        __syncthreads();

        float acc[8];
        #pragma unroll
        for (int r = 0; r < 8; r++) acc[r] = bb;

        #pragma unroll 4
        for (int kq = 0; kq < 32; kq++) {
            const float4 wq = Wq[kq][lane];
            #pragma unroll
            for (int r = 0; r < 8; r++) {
                const float4 xq = xs[wv][r][kq];   // wave-uniform broadcast read
                acc[r] = fmaf(wq.x, xq.x, acc[r]);
                acc[r] = fmaf(wq.y, xq.y, acc[r]);
                acc[r] = fmaf(wq.z, xq.z, acc[r]);
                acc[r] = fmaf(wq.w, xq.w, acc[r]);
            }
        }

        #pragma unroll
        for (int r = 0; r < 8; r++) {
            const int node = node0 + r;
            const float v = acc[r];
            float p = v * al, q = v * ar;
            for (int s = 32; s; s >>= 1) {
                p += __shfl_down(p, s);
                q += __shfl_down(q, s);
            }
            if (node < n) {
                hh[(size_t)node * OUTF + lane] = __float2half(v);
                if (lane == 0) { sl[node] = p; sr[node] = q; }
            }
        }
        __syncthreads();
    }
}

// ---------------- coarse radix by src>>7 (LDS atomics only) ----------------
__global__ __launch_bounds__(256) void count_coarse(
    const int* __restrict__ src, int* __restrict__ M, int E)
{
    __shared__ int hist[NB];
    for (int i = threadIdx.x; i < NB; i += 256) hist[i] = 0;
    __syncthreads();
    const int chunk = (E + NBLK - 1) / NBLK;
    const int lo = blockIdx.x * chunk;
    const int hi = min(E, lo + chunk);
    for (int e = lo + (int)threadIdx.x; e < hi; e += 256)
        atomicAdd(&hist[src[e] >> LOCB], 1);
    __syncthreads();
    for (int i = threadIdx.x; i < NB; i += 256)
        M[blockIdx.x * NB + i] = hist[i];
}

// in-place exclusive column prefix: M[b][B] <- sum_{b'<b} cnt[b'][B]; colsum[B]=total
// 8-deep load batching keeps 8 L2 reads in flight per thread (was: 1, ~45us kernel)
__global__ __launch_bounds__(256) void colscan_kernel(
    int* __restrict__ M, int* __restrict__ colsum)
{
    const int B = blockIdx.x * 256 + (int)threadIdx.x;   // grid NB/256
    int run = 0;
    for (int b = 0; b < NBLK; b += 8) {
        int c[8];
        #pragma unroll
        for (int k = 0; k < 8; k++) c[k] = M[(size_t)(b + k) * NB + B];
        #pragma unroll
        for (int k = 0; k < 8; k++) { M[(size_t)(b + k) * NB + B] = run; run += c[k]; }
    }
    colsum[B] = run;
}

__global__ __launch_bounds__(1024) void scan_bucket(
    const int* __restrict__ colsum, int* __restrict__ bbase)
{
    __shared__ int part[NB];
    const int t = threadIdx.x;
    const int own = colsum[t];
    part[t] = own;
    __syncthreads();
    for (int d = 1; d < NB; d <<= 1) {
        int v = (t >= d) ? part[t - d] : 0;
        __syncthreads();
        part[t] += v;
        __syncthreads();
    }
    bbase[t] = part[t] - own;
    if (t == NB - 1) bbase[NB] = part[t];
}

// scatter + fused edge-weight compute: pk64 = w_fp16<<32 | (src&127)<<17 | dst
__global__ __launch_bounds__(256) void scatter_coarse(
    const int* __restrict__ src, const int* __restrict__ dst,
    const int* __restrict__ M, const int* __restrict__ bbase,
    const float* __restrict__ sl, const float* __restrict__ sr,
    unsigned long long* __restrict__ pk64, int E)
{
    __shared__ int cur[NB];
    for (int i = threadIdx.x; i < NB; i += 256)
        cur[i] = M[blockIdx.x * NB + i] + bbase[i];
    __syncthreads();
    const int chunk = (E + NBLK - 1) / NBLK;
    const int lo = blockIdx.x * chunk;
    const int hi = min(E, lo + chunk);
    for (int e = lo + (int)threadIdx.x; e < hi; e += 256) {
        const int s = src[e];
        const int d = dst[e];
        const float sc = sl[s] + sr[d];              // random 4B gathers, L2-resident
        const float lr = sc > 0.f ? sc : ALPHA * sc;
        const unsigned short w16 = __half_as_ushort(__float2half(__expf(-lr)));
        const int p = atomicAdd(&cur[s >> LOCB], 1);
        pk64[p] = ((unsigned long long)w16 << 32) |
                  (unsigned int)(((s & 127) << 17) | d);   // dst < 2^17
    }
}

// ---------------- finalize: per-bucket local CSR -> off, bdst, wgt ----------------
__global__ __launch_bounds__(256) void finalize_kernel(
    const unsigned long long* __restrict__ pk64, const int* __restrict__ bbase,
    int* __restrict__ off, int* __restrict__ bdst, __half* __restrict__ wgt,
    int n, int E)
{
    __shared__ int lhist[128];
    __shared__ int sc[256];
    __shared__ int cur2[128];

    const int B  = blockIdx.x;
    const int b0 = bbase[B], b1 = bbase[B + 1];
    const int t  = threadIdx.x;

    if (t < 128) lhist[t] = 0;
    __syncthreads();
    for (int j = b0 + t; j < b1; j += 256)
        atomicAdd(&lhist[((unsigned int)pk64[j] >> 17) & 127], 1);
    __syncthreads();

    const int v = (t < 128) ? lhist[t] : 0;
    sc[t] = v;
    __syncthreads();
    for (int d = 1; d < 256; d <<= 1) {
        int u = (t >= d) ? sc[t - d] : 0;
        __syncthreads();
        sc[t] += u;
        __syncthreads();
    }
    if (t < 128) {
        const int base = b0 + sc[t] - v;
        const int s = (B << LOCB) + t;
        if (s < n) off[s] = base;
        cur2[t] = base;
    }
    if (B == 0 && t == 0) off[n] = E;
    __syncthreads();

    for (int j = b0 + t; j < b1; j += 256) {
        const unsigned long long w = pk64[j];
        const unsigned int lowb = (unsigned int)w;
        const int p = atomicAdd(&cur2[(lowb >> 17) & 127], 1);
        bdst[p] = (int)(lowb & 0x1FFFF);                       // L2-local stores
        wgt[p]  = __ushort_as_half((unsigned short)(w >> 32));
    }
}

// ---- flat gather + LN + ELU: lane owns 4 features, wave does 4 edges/load ----
__global__ __launch_bounds__(256) void gather_kernel(
    const __half* __restrict__ hh,
    const int* __restrict__ off, const int* __restrict__ bdst,
    const __half* __restrict__ wgt,
    const float* __restrict__ gamma, const float* __restrict__ beta,
    float* __restrict__ out, int n)
{
    const int lane  = threadIdx.x & 63;
    const int fgrp  = lane & 15;        // features 4*fgrp .. 4*fgrp+3
    const int equad = lane >> 4;        // which edge of each group of 4
    const int wave  = (int)((blockIdx.x * blockDim.x + threadIdx.x) >> 6);
    const int nw    = (int)((gridDim.x * blockDim.x) >> 6);
    const float4 gm4 = ((const float4*)gamma)[fgrp];
    const float4 bt4 = ((const float4*)beta)[fgrp];

    for (int i = wave; i < n; i += nw) {
        const int o0 = off[i], o1 = off[i + 1];
        float4 acc = make_float4(0.f, 0.f, 0.f, 0.f);

        for (int base = o0; base < o1; base += 64) {
            const int j = base + lane;
            int d = 0; float w = 0.f;
            if (j < o1) { d = bdst[j]; w = __half2float(wgt[j]); }
            const int m = min(64, o1 - base);

            for (int t = 0; t < m; t += 8) {       // 8 edges (2 b64 loads) in flight
                const int e0 = t + equad, e1 = t + 4 + equad;
                int   dd0 = __shfl(d, e0); float ww0 = __shfl(w, e0);
                int   dd1 = __shfl(d, e1); float ww1 = __shfl(w, e1);
                if (e0 >= m) { dd0 = 0; ww0 = 0.f; }
                if (e1 >= m) { dd1 = 0; ww1 = 0.f; }
                const uint2 u0 = ((const uint2*)hh)[(size_t)dd0 * 16 + fgrp];
                const uint2 u1 = ((const uint2*)hh)[(size_t)dd1 * 16 + fgrp];
                const float2 f00 = __half22float2(*(const __half2*)&u0.x);
                const float2 f01 = __half22float2(*(const __half2*)&u0.y);
                const float2 f10 = __half22float2(*(const __half2*)&u1.x);
                const float2 f11 = __half22float2(*(const __half2*)&u1.y);
                acc.x = fmaf(ww0, f00.x, acc.x); acc.y = fmaf(ww0, f00.y, acc.y);
                acc.z = fmaf(ww0, f01.x, acc.z); acc.w = fmaf(ww0, f01.y, acc.w);
                acc.x = fmaf(ww1, f10.x, acc.x); acc.y = fmaf(ww1, f10.y, acc.y);
                acc.z = fmaf(ww1, f11.x, acc.z); acc.w = fmaf(ww1, f11.y, acc.w);
            }
        }

        // merge edge-quads: butterfly over lane bits 4,5
        acc.x += __shfl_xor(acc.x, 16); acc.x += __shfl_xor(acc.x, 32);
        acc.y += __shfl_xor(acc.y, 16); acc.y += __shfl_xor(acc.y, 32);
        acc.z += __shfl_xor(acc.z, 16); acc.z += __shfl_xor(acc.z, 32);
        acc.w += __shfl_xor(acc.w, 16); acc.w += __shfl_xor(acc.w, 32);

        // LayerNorm (two-pass, biased var) over 64 features spread across 16 fgrps
        float s1 = acc.x + acc.y + acc.z + acc.w;
        #pragma unroll
        for (int dd = 1; dd < 16; dd <<= 1) s1 += __shfl_xor(s1, dd);
        const float mu = s1 * (1.f / 64.f);
        const float dx = acc.x - mu, dy = acc.y - mu, dz = acc.z - mu, dw = acc.w - mu;
        float s2 = dx * dx + dy * dy + dz * dz + dw * dw;
        #pragma unroll
        for (int dd = 1; dd < 16; dd <<= 1) s2 += __shfl_xor(s2, dd);
        const float rs = rsqrtf(s2 * (1.f / 64.f) + LN_EPS);

        float4 y;
        y.x = dx * rs * gm4.x + bt4.x;
        y.y = dy * rs * gm4.y + bt4.y;
        y.z = dz * rs * gm4.z + bt4.z;
        y.w = dw * rs * gm4.w + bt4.w;
        y.x = y.x > 0.f ? y.x : expm1f(y.x);
        y.y = y.y > 0.f ? y.y : expm1f(y.y);
        y.z = y.z > 0.f ? y.z : expm1f(y.z);
        y.w = y.w > 0.f ? y.w : expm1f(y.w);
        if (equad == 0)
            ((float4*)out)[(size_t)i * 16 + fgrp] = y;
    }
}

// ---------------- launch ----------------
extern "C" void kernel_launch(void* const* d_in, const int* in_sizes, int n_in,
                              void* d_out, int out_size, void* d_ws, size_t ws_size,
                              hipStream_t stream)
{
    const float* x     = (const float*)d_in[0];
    const int*   edge  = (const int*)  d_in[1];
    const float* W     = (const float*)d_in[2];
    const float* b     = (const float*)d_in[3];
    const float* a     = (const float*)d_in[4];
    const float* gamma = (const float*)d_in[5];
    const float* beta  = (const float*)d_in[6];
    float* out = (float*)d_out;

    const int n = in_sizes[0] / INF_;   // 100000
    const int E = in_sizes[1] / 2;      // 3200000
    const int* src = edge;
    const int* dst = edge + E;
    const int nbuck = (n + 127) >> 7;   // 782 buckets

    char* ws = (char*)d_ws;
    size_t offb = 0;
    auto alloc = [&](size_t bytes) -> void* {
        void* p = ws + offb;
        offb = (offb + bytes + 255) & ~(size_t)255;
        return p;
    };
    __half* hh    = (__half*)alloc((size_t)n * OUTF * 2);
    float*  sl    = (float*) alloc((size_t)n * 4);
    float*  sr    = (float*) alloc((size_t)n * 4);
    int*    M     = (int*)   alloc((size_t)NBLK * NB * 4);   // 2 MB
    int*    colsum= (int*)   alloc((size_t)NB * 4);
    int*    bbase = (int*)   alloc((size_t)(NB + 1) * 4);
    int*    off   = (int*)   alloc((size_t)(n + 1) * 4);
    unsigned long long* pk64 = (unsigned long long*)alloc((size_t)E * 8);
    int*    bdst  = (int*)   alloc((size_t)E * 4);
    __half* wgt   = (__half*)alloc((size_t)E * 2);

    hipLaunchKernelGGL(count_coarse,    dim3(NBLK),   dim3(256),  0, stream, src, M, E);
    hipLaunchKernelGGL(colscan_kernel,  dim3(NB/256), dim3(256),  0, stream, M, colsum);
    hipLaunchKernelGGL(scan_bucket,     dim3(1),      dim3(1024), 0, stream, colsum, bbase);
    hipLaunchKernelGGL(gemm_kernel,     dim3(1024),   dim3(256),  0, stream, x, W, b, a, hh, sl, sr, n);
    hipLaunchKernelGGL(scatter_coarse,  dim3(NBLK),   dim3(256),  0, stream, src, dst, M, bbase, sl, sr, pk64, E);
    hipLaunchKernelGGL(finalize_kernel, dim3(nbuck),  dim3(256),  0, stream, pk64, bbase, off, bdst, wgt, n, E);
    hipLaunchKernelGGL(gather_kernel,   dim3(4096),   dim3(256),  0, stream, hh, off, bdst, wgt, gamma, beta, out, n);
}

// Round 8
// 396.273 us; speedup vs baseline: 1.0048x; 1.0048x over previous
//
#include <hip/hip_runtime.h>
#include <hip/hip_fp16.h>
#include <cstdint>
#include <cstddef>

#define INF_  128
#define OUTF  64
#define ALPHA 0.2f
#define LN_EPS 1e-5f

#define NB    1024        // coarse buckets (src >> 7)
#define LOCB  7           // 128 local nodes per bucket
#define NBLK  2048        // edge-partition blocks (8 blocks/CU: latency hiding)
#define MAXK  32          // max edges per finalize thread in register path (+64 sigma)

// ---------------- GEMM: h(fp16) = x @ W^T + b, sl = h@a_l, sr = h@a_r ----------------
__global__ __launch_bounds__(256) void gemm_kernel(
    const float* __restrict__ x, const float* __restrict__ W,
    const float* __restrict__ b, const float* __restrict__ a,
    __half* __restrict__ hh, float* __restrict__ sl, float* __restrict__ sr, int n)
{
    __shared__ float4 Wq[32][64];          // Wq[kq][o]: lane-stride 16B, conflict-free
    __shared__ float4 xs[4][8][32];

    const int tid  = threadIdx.x;
    const int lane = tid & 63;
    const int wv   = tid >> 6;

    for (int idx = tid; idx < 2048; idx += 256) {
        int kq = idx >> 6, o = idx & 63;
        Wq[kq][o] = ((const float4*)W)[o * 32 + kq];
    }
    __syncthreads();

    const float bb = b[lane];
    const float al = a[lane];
    const float ar = a[OUTF + lane];

    const int ngroups = (n + 31) >> 5;
    for (int g = blockIdx.x; g < ngroups; g += gridDim.x) {
        const int node0 = g * 32 + wv * 8;
        for (int t = lane; t < 8 * 32; t += 64) {
            int r = t >> 5, q = t & 31;
            int nd = node0 + r; if (nd >= n) nd = 0;
            xs[wv][r][q] = ((const float4*)x)[(size_t)nd * 32 + q];
        }
        __syncthreads();

        float acc[8];
        #pragma unroll
        for (int r = 0; r < 8; r++) acc[r] = bb;

        #pragma unroll 4
        for (int kq = 0; kq < 32; kq++) {
            const float4 wq = Wq[kq][lane];
            #pragma unroll
            for (int r = 0; r < 8; r++) {
                const float4 xq = xs[wv][r][kq];   // wave-uniform broadcast read
                acc[r] = fmaf(wq.x, xq.x, acc[r]);
                acc[r] = fmaf(wq.y, xq.y, acc[r]);
                acc[r] = fmaf(wq.z, xq.z, acc[r]);
                acc[r] = fmaf(wq.w, xq.w, acc[r]);
            }
        }

        #pragma unroll
        for (int r = 0; r < 8; r++) {
            const int node = node0 + r;
            const float v = acc[r];
            float p = v * al, q = v * ar;
            for (int s = 32; s; s >>= 1) {
                p += __shfl_down(p, s);
                q += __shfl_down(q, s);
            }
            if (node < n) {
                hh[(size_t)node * OUTF + lane] = __float2half(v);
                if (lane == 0) { sl[node] = p; sr[node] = q; }
            }
        }
        __syncthreads();
    }
}

// ---------------- coarse radix by src>>7 (LDS atomics only) ----------------
__global__ __launch_bounds__(256) void count_coarse(
    const int* __restrict__ src, int* __restrict__ M, int E)
{
    __shared__ int hist[NB];
    for (int i = threadIdx.x; i < NB; i += 256) hist[i] = 0;
    __syncthreads();
    const int chunk = (E + NBLK - 1) / NBLK;
    const int lo = blockIdx.x * chunk;
    const int hi = min(E, lo + chunk);
    for (int e = lo + (int)threadIdx.x; e < hi; e += 256)
        atomicAdd(&hist[src[e] >> LOCB], 1);
    __syncthreads();
    for (int i = threadIdx.x; i < NB; i += 256)
        M[blockIdx.x * NB + i] = hist[i];
}

// in-place exclusive column prefix (coalesced across lanes); colsum[B]=total
__global__ __launch_bounds__(256) void colscan_kernel(
    int* __restrict__ M, int* __restrict__ colsum)
{
    const int B = blockIdx.x * 256 + (int)threadIdx.x;   // grid NB/256
    int run = 0;
    for (int b = 0; b < NBLK; b += 8) {
        int c[8];
        #pragma unroll
        for (int k = 0; k < 8; k++) c[k] = M[(size_t)(b + k) * NB + B];
        #pragma unroll
        for (int k = 0; k < 8; k++) { M[(size_t)(b + k) * NB + B] = run; run += c[k]; }
    }
    colsum[B] = run;
}

__global__ __launch_bounds__(1024) void scan_bucket(
    const int* __restrict__ colsum, int* __restrict__ bbase)
{
    __shared__ int part[NB];
    const int t = threadIdx.x;
    const int own = colsum[t];
    part[t] = own;
    __syncthreads();
    for (int d = 1; d < NB; d <<= 1) {
        int v = (t >= d) ? part[t - d] : 0;
        __syncthreads();
        part[t] += v;
        __syncthreads();
    }
    bbase[t] = part[t] - own;
    if (t == NB - 1) bbase[NB] = part[t];
}

// slim scatter: coalesced loads -> LDS cursor -> 4B random store. No gathers, no exp.
__global__ __launch_bounds__(256) void scatter_coarse(
    const int* __restrict__ src, const int* __restrict__ dst,
    const int* __restrict__ M, const int* __restrict__ bbase,
    int* __restrict__ pk, int E)
{
    __shared__ int cur[NB];
    for (int i = threadIdx.x; i < NB; i += 256)
        cur[i] = M[blockIdx.x * NB + i] + bbase[i];
    __syncthreads();
    const int chunk = (E + NBLK - 1) / NBLK;
    const int lo = blockIdx.x * chunk;
    const int hi = min(E, lo + chunk);
    for (int e = lo + (int)threadIdx.x; e < hi; e += 256) {
        const int s = src[e];
        const int p = atomicAdd(&cur[s >> LOCB], 1);
        pk[p] = ((s & 127) << 17) | dst[e];      // dst < 2^17
    }
}

// ---------------- finalize: per-bucket local CSR + edge weights ----------------
// pk read ONCE into registers; sr[d] gathers + expf issued in pass 1 so their
// latency overlaps the hist/scan barriers; pass 2 places from registers.
__global__ __launch_bounds__(256) void finalize_kernel(
    const int* __restrict__ pk, const int* __restrict__ bbase,
    const float* __restrict__ sl, const float* __restrict__ sr,
    int* __restrict__ off, int* __restrict__ bdst, __half* __restrict__ wgt,
    int n, int E)
{
    __shared__ int   lhist[128];
    __shared__ int   sc[256];
    __shared__ int   cur2[128];
    __shared__ float lsl[128];

    const int B  = blockIdx.x;
    const int b0 = bbase[B], b1 = bbase[B + 1];
    const int cnt = b1 - b0;
    const int t  = threadIdx.x;

    if (t < 128) {
        lhist[t] = 0;
        const int s = (B << LOCB) + t;
        lsl[t] = (s < n) ? sl[s] : 0.f;
    }
    __syncthreads();

    const int myn = (cnt > t) ? (cnt - t + 255) >> 8 : 0;   // edges this thread owns
    int   pkr[MAXK];
    float wf[MAXK];
    #pragma unroll
    for (int k = 0; k < MAXK; k++) {
        if (k < myn) {
            const int v = pk[b0 + t + (k << 8)];
            pkr[k] = v;
            const int s = (v >> 17) & 127;
            atomicAdd(&lhist[s], 1);
            const float scv = lsl[s] + sr[v & 0x1FFFF];   // random L2 gather in flight
            const float lr  = scv > 0.f ? scv : ALPHA * scv;
            wf[k] = __expf(-lr);
        }
    }
    // statistically-impossible overflow path (cnt > MAXK*256): count the rest
    for (int k = MAXK; k < myn; k++)
        atomicAdd(&lhist[(pk[b0 + t + (k << 8)] >> 17) & 127], 1);
    __syncthreads();

    const int v = (t < 128) ? lhist[t] : 0;
    sc[t] = v;
    __syncthreads();
    for (int d = 1; d < 256; d <<= 1) {
        int u = (t >= d) ? sc[t - d] : 0;
        __syncthreads();
        sc[t] += u;
        __syncthreads();
    }
    if (t < 128) {
        const int base = b0 + sc[t] - v;
        const int s = (B << LOCB) + t;
        if (s < n) off[s] = base;
        cur2[t] = base;
    }
    if (B == 0 && t == 0) off[n] = E;
    __syncthreads();

    #pragma unroll
    for (int k = 0; k < MAXK; k++) {
        if (k < myn) {
            const int w = pkr[k];
            const int p = atomicAdd(&cur2[(w >> 17) & 127], 1);
            bdst[p] = w & 0x1FFFF;                 // L2-local stores
            wgt[p]  = __float2half(wf[k]);
        }
    }
    for (int k = MAXK; k < myn; k++) {
        const int w = pk[b0 + t + (k << 8)];
        const int s = (w >> 17) & 127, d = w & 0x1FFFF;
        const float scv = lsl[s] + sr[d];
        const float lr  = scv > 0.f ? scv : ALPHA * scv;
        const int p = atomicAdd(&cur2[s], 1);
        bdst[p] = d;
        wgt[p]  = __float2half(__expf(-lr));
    }
}

// ---- flat gather + LN + ELU: lane owns 4 features, wave does 4 edges/load ----
__global__ __launch_bounds__(256) void gather_kernel(
    const __half* __restrict__ hh,
    const int* __restrict__ off, const int* __restrict__ bdst,
    const __half* __restrict__ wgt,
    const float* __restrict__ gamma, const float* __restrict__ beta,
    float* __restrict__ out, int n)
{
    const int lane  = threadIdx.x & 63;
    const int fgrp  = lane & 15;        // features 4*fgrp .. 4*fgrp+3
    const int equad = lane >> 4;        // which edge of each group of 4
    const int wave  = (int)((blockIdx.x * blockDim.x + threadIdx.x) >> 6);
    const int nw    = (int)((gridDim.x * blockDim.x) >> 6);
    const float4 gm4 = ((const float4*)gamma)[fgrp];
    const float4 bt4 = ((const float4*)beta)[fgrp];

    for (int i = wave; i < n; i += nw) {
        const int o0 = off[i], o1 = off[i + 1];
        float4 acc = make_float4(0.f, 0.f, 0.f, 0.f);

        for (int base = o0; base < o1; base += 64) {
            const int j = base + lane;
            int d = 0; float w = 0.f;
            if (j < o1) { d = bdst[j]; w = __half2float(wgt[j]); }
            const int m = min(64, o1 - base);

            for (int t = 0; t < m; t += 8) {       // 8 edges (2 b64 loads) in flight
                const int e0 = t + equad, e1 = t + 4 + equad;
                int   dd0 = __shfl(d, e0); float ww0 = __shfl(w, e0);
                int   dd1 = __shfl(d, e1); float ww1 = __shfl(w, e1);
                if (e0 >= m) { dd0 = 0; ww0 = 0.f; }
                if (e1 >= m) { dd1 = 0; ww1 = 0.f; }
                const uint2 u0 = ((const uint2*)hh)[(size_t)dd0 * 16 + fgrp];
                const uint2 u1 = ((const uint2*)hh)[(size_t)dd1 * 16 + fgrp];
                const float2 f00 = __half22float2(*(const __half2*)&u0.x);
                const float2 f01 = __half22float2(*(const __half2*)&u0.y);
                const float2 f10 = __half22float2(*(const __half2*)&u1.x);
                const float2 f11 = __half22float2(*(const __half2*)&u1.y);
                acc.x = fmaf(ww0, f00.x, acc.x); acc.y = fmaf(ww0, f00.y, acc.y);
                acc.z = fmaf(ww0, f01.x, acc.z); acc.w = fmaf(ww0, f01.y, acc.w);
                acc.x = fmaf(ww1, f10.x, acc.x); acc.y = fmaf(ww1, f10.y, acc.y);
                acc.z = fmaf(ww1, f11.x, acc.z); acc.w = fmaf(ww1, f11.y, acc.w);
            }
        }

        // merge edge-quads: butterfly over lane bits 4,5
        acc.x += __shfl_xor(acc.x, 16); acc.x += __shfl_xor(acc.x, 32);
        acc.y += __shfl_xor(acc.y, 16); acc.y += __shfl_xor(acc.y, 32);
        acc.z += __shfl_xor(acc.z, 16); acc.z += __shfl_xor(acc.z, 32);
        acc.w += __shfl_xor(acc.w, 16); acc.w += __shfl_xor(acc.w, 32);

        // LayerNorm (biased var) over 64 features spread across 16 fgrps
        float s1 = acc.x + acc.y + acc.z + acc.w;
        #pragma unroll
        for (int dd = 1; dd < 16; dd <<= 1) s1 += __shfl_xor(s1, dd);
        const float mu = s1 * (1.f / 64.f);
        const float dx = acc.x - mu, dy = acc.y - mu, dz = acc.z - mu, dw = acc.w - mu;
        float s2 = dx * dx + dy * dy + dz * dz + dw * dw;
        #pragma unroll
        for (int dd = 1; dd < 16; dd <<= 1) s2 += __shfl_xor(s2, dd);
        const float rs = rsqrtf(s2 * (1.f / 64.f) + LN_EPS);

        float4 y;
        y.x = dx * rs * gm4.x + bt4.x;
        y.y = dy * rs * gm4.y + bt4.y;
        y.z = dz * rs * gm4.z + bt4.z;
        y.w = dw * rs * gm4.w + bt4.w;
        y.x = y.x > 0.f ? y.x : expm1f(y.x);
        y.y = y.y > 0.f ? y.y : expm1f(y.y);
        y.z = y.z > 0.f ? y.z : expm1f(y.z);
        y.w = y.w > 0.f ? y.w : expm1f(y.w);
        if (equad == 0)
            ((float4*)out)[(size_t)i * 16 + fgrp] = y;
    }
}

// ---------------- launch ----------------
extern "C" void kernel_launch(void* const* d_in, const int* in_sizes, int n_in,
                              void* d_out, int out_size, void* d_ws, size_t ws_size,
                              hipStream_t stream)
{
    const float* x     = (const float*)d_in[0];
    const int*   edge  = (const int*)  d_in[1];
    const float* W     = (const float*)d_in[2];
    const float* b     = (const float*)d_in[3];
    const float* a     = (const float*)d_in[4];
    const float* gamma = (const float*)d_in[5];
    const float* beta  = (const float*)d_in[6];
    float* out = (float*)d_out;

    const int n = in_sizes[0] / INF_;   // 100000
    const int E = in_sizes[1] / 2;      // 3200000
    const int* src = edge;
    const int* dst = edge + E;
    const int nbuck = (n + 127) >> 7;   // 782 buckets

    char* ws = (char*)d_ws;
    size_t offb = 0;
    auto alloc = [&](size_t bytes) -> void* {
        void* p = ws + offb;
        offb = (offb + bytes + 255) & ~(size_t)255;
        return p;
    };
    __half* hh    = (__half*)alloc((size_t)n * OUTF * 2);
    float*  sl    = (float*) alloc((size_t)n * 4);
    float*  sr    = (float*) alloc((size_t)n * 4);
    int*    M     = (int*)   alloc((size_t)NBLK * NB * 4);   // 8 MB
    int*    colsum= (int*)   alloc((size_t)NB * 4);
    int*    bbase = (int*)   alloc((size_t)(NB + 1) * 4);
    int*    off   = (int*)   alloc((size_t)(n + 1) * 4);
    int*    pk    = (int*)   alloc((size_t)E * 4);
    int*    bdst  = (int*)   alloc((size_t)E * 4);
    __half* wgt   = (__half*)alloc((size_t)E * 2);

    hipLaunchKernelGGL(count_coarse,    dim3(NBLK),   dim3(256),  0, stream, src, M, E);
    hipLaunchKernelGGL(colscan_kernel,  dim3(NB/256), dim3(256),  0, stream, M, colsum);
    hipLaunchKernelGGL(scan_bucket,     dim3(1),      dim3(1024), 0, stream, colsum, bbase);
    hipLaunchKernelGGL(scatter_coarse,  dim3(NBLK),   dim3(256),  0, stream, src, dst, M, bbase, pk, E);
    hipLaunchKernelGGL(gemm_kernel,     dim3(1024),   dim3(256),  0, stream, x, W, b, a, hh, sl, sr, n);
    hipLaunchKernelGGL(finalize_kernel, dim3(nbuck),  dim3(256),  0, stream, pk, bbase, sl, sr, off, bdst, wgt, n, E);
    hipLaunchKernelGGL(gather_kernel,   dim3(4096),   dim3(256),  0, stream, hh, off, bdst, wgt, gamma, beta, out, n);
}

// Round 9
// 339.750 us; speedup vs baseline: 1.1720x; 1.1664x over previous
//
#include <hip/hip_runtime.h>
#include <hip/hip_fp16.h>
#include <cstdint>
#include <cstddef>

#define INF_  128
#define OUTF  64
#define ALPHA 0.2f
#define LN_EPS 1e-5f

#define NB    1024        // coarse buckets (src >> 7)
#define LOCB  7           // 128 local nodes per bucket
#define NBLK  2048        // edge-partition blocks (8 blocks/CU: latency hiding)
#define MAXK  32          // max edges per finalize thread in register path

typedef __attribute__((ext_vector_type(8))) _Float16 half8;
typedef __attribute__((ext_vector_type(4))) float    f32x4;

// ---------------- MFMA GEMM: h(fp16) = x @ W^T + b, sl = h@a_l, sr = h@a_r ----
// wave = 16 nodes x 64 outs. B-frags (W, fp16) pinned in VGPRs; A-frags loaded
// direct from global (no LDS, no barrier in K-loop). B-frag t covers outs
// 4*col+t so per-node epilogue values are contiguous -> coalesced ushort4 store.
__global__ __launch_bounds__(256) void gemm_kernel(
    const float* __restrict__ x, const float* __restrict__ W,
    const float* __restrict__ b, const float* __restrict__ a,
    __half* __restrict__ hh, float* __restrict__ sl, float* __restrict__ sr, int n)
{
    __shared__ half8 wfrag_lds[16][64];   // [(c*4+t)][lane], 16 KB

    const int tid  = threadIdx.x;
    const int lane = tid & 63;
    const int wv   = tid >> 6;
    const int col  = lane & 15;
    const int quad = lane >> 4;

    // stage B-frags: entry (c,t,lane) = W[4*(lane&15)+t][32c+8*(lane>>4)..+7] fp16
    for (int idx = tid; idx < 1024; idx += 256) {
        const int l  = idx & 63, ct = idx >> 6;
        const int c  = ct >> 2,  t  = ct & 3;
        const int row = 4 * (l & 15) + t;
        const int k0  = 32 * c + 8 * (l >> 4);
        const float4 f0 = ((const float4*)W)[row * 32 + (k0 >> 2)];
        const float4 f1 = ((const float4*)W)[row * 32 + (k0 >> 2) + 1];
        half8 h;
        h[0] = (_Float16)f0.x; h[1] = (_Float16)f0.y;
        h[2] = (_Float16)f0.z; h[3] = (_Float16)f0.w;
        h[4] = (_Float16)f1.x; h[5] = (_Float16)f1.y;
        h[6] = (_Float16)f1.z; h[7] = (_Float16)f1.w;
        wfrag_lds[ct][l] = h;
    }
    __syncthreads();

    half8 bf[4][4];                       // [chunk][t], 64 VGPRs, live all kernel
    #pragma unroll
    for (int c = 0; c < 4; c++)
        #pragma unroll
        for (int t = 0; t < 4; t++)
            bf[c][t] = wfrag_lds[c * 4 + t][lane];   // lane-stride 16B, conflict-free

    const float4 b4  = ((const float4*)b)[col];      // b[4col..4col+3]
    const float4 al4 = ((const float4*)a)[col];      // a_l[4col..4col+3]
    const float4 ar4 = ((const float4*)a)[16 + col]; // a_r[4col..4col+3]

    const int ntile  = (n + 15) >> 4;
    const int wgid   = blockIdx.x * 4 + wv;
    const int nwaves = gridDim.x * 4;

    for (int tile = wgid; tile < ntile; tile += nwaves) {
        const int node0 = tile << 4;
        const int xr    = min(node0 + col, n - 1);       // A-row this lane feeds
        const float* xrow = x + (size_t)xr * INF_ + 8 * quad;

        f32x4 acc0 = {0,0,0,0}, acc1 = {0,0,0,0}, acc2 = {0,0,0,0}, acc3 = {0,0,0,0};
        #pragma unroll
        for (int c = 0; c < 4; c++) {
            const float4 f0 = *(const float4*)(xrow + 32 * c);
            const float4 f1 = *(const float4*)(xrow + 32 * c + 4);
            half8 af;
            af[0] = (_Float16)f0.x; af[1] = (_Float16)f0.y;
            af[2] = (_Float16)f0.z; af[3] = (_Float16)f0.w;
            af[4] = (_Float16)f1.x; af[5] = (_Float16)f1.y;
            af[6] = (_Float16)f1.z; af[7] = (_Float16)f1.w;
            acc0 = __builtin_amdgcn_mfma_f32_16x16x32_f16(af, bf[c][0], acc0, 0, 0, 0);
            acc1 = __builtin_amdgcn_mfma_f32_16x16x32_f16(af, bf[c][1], acc1, 0, 0, 0);
            acc2 = __builtin_amdgcn_mfma_f32_16x16x32_f16(af, bf[c][2], acc2, 0, 0, 0);
            acc3 = __builtin_amdgcn_mfma_f32_16x16x32_f16(af, bf[c][3], acc3, 0, 0, 0);
        }

        // D layout: row(node) = quad*4+reg, col(out-group) = lane&15
        #pragma unroll
        for (int reg = 0; reg < 4; reg++) {
            const int node = node0 + quad * 4 + reg;
            const float v0 = acc0[reg] + b4.x;
            const float v1 = acc1[reg] + b4.y;
            const float v2 = acc2[reg] + b4.z;
            const float v3 = acc3[reg] + b4.w;
            float p = v0 * al4.x + v1 * al4.y + v2 * al4.z + v3 * al4.w;
            float q = v0 * ar4.x + v1 * ar4.y + v2 * ar4.z + v3 * ar4.w;
            p += __shfl_xor(p, 1); p += __shfl_xor(p, 2);
            p += __shfl_xor(p, 4); p += __shfl_xor(p, 8);
            q += __shfl_xor(q, 1); q += __shfl_xor(q, 2);
            q += __shfl_xor(q, 4); q += __shfl_xor(q, 8);
            if (node < n) {
                ushort4 u;
                u.x = __half_as_ushort(__float2half(v0));
                u.y = __half_as_ushort(__float2half(v1));
                u.z = __half_as_ushort(__float2half(v2));
                u.w = __half_as_ushort(__float2half(v3));
                ((ushort4*)hh)[(size_t)node * 16 + col] = u;   // 4 nodes x 128B / instr
                if (col == 0) { sl[node] = p; sr[node] = q; }
            }
        }
    }
}

// ---------------- coarse radix by src>>7 (LDS atomics only) ----------------
__global__ __launch_bounds__(256) void count_coarse(
    const int* __restrict__ src, int* __restrict__ M, int E)
{
    __shared__ int hist[NB];
    for (int i = threadIdx.x; i < NB; i += 256) hist[i] = 0;
    __syncthreads();
    const int chunk = (E + NBLK - 1) / NBLK;
    const int lo = blockIdx.x * chunk;
    const int hi = min(E, lo + chunk);
    for (int e = lo + (int)threadIdx.x; e < hi; e += 256)
        atomicAdd(&hist[src[e] >> LOCB], 1);
    __syncthreads();
    for (int i = threadIdx.x; i < NB; i += 256)
        M[blockIdx.x * NB + i] = hist[i];
}

// in-place exclusive column prefix (coalesced across lanes); colsum[B]=total
__global__ __launch_bounds__(256) void colscan_kernel(
    int* __restrict__ M, int* __restrict__ colsum)
{
    const int B = blockIdx.x * 256 + (int)threadIdx.x;   // grid NB/256
    int run = 0;
    for (int b = 0; b < NBLK; b += 8) {
        int c[8];
        #pragma unroll
        for (int k = 0; k < 8; k++) c[k] = M[(size_t)(b + k) * NB + B];
        #pragma unroll
        for (int k = 0; k < 8; k++) { M[(size_t)(b + k) * NB + B] = run; run += c[k]; }
    }
    colsum[B] = run;
}

__global__ __launch_bounds__(1024) void scan_bucket(
    const int* __restrict__ colsum, int* __restrict__ bbase)
{
    __shared__ int part[NB];
    const int t = threadIdx.x;
    const int own = colsum[t];
    part[t] = own;
    __syncthreads();
    for (int d = 1; d < NB; d <<= 1) {
        int v = (t >= d) ? part[t - d] : 0;
        __syncthreads();
        part[t] += v;
        __syncthreads();
    }
    bbase[t] = part[t] - own;
    if (t == NB - 1) bbase[NB] = part[t];
}

// slim scatter: coalesced loads -> LDS cursor -> 4B random store.
__global__ __launch_bounds__(256) void scatter_coarse(
    const int* __restrict__ src, const int* __restrict__ dst,
    const int* __restrict__ M, const int* __restrict__ bbase,
    int* __restrict__ pk, int E)
{
    __shared__ int cur[NB];
    for (int i = threadIdx.x; i < NB; i += 256)
        cur[i] = M[blockIdx.x * NB + i] + bbase[i];
    __syncthreads();
    const int chunk = (E + NBLK - 1) / NBLK;
    const int lo = blockIdx.x * chunk;
    const int hi = min(E, lo + chunk);
    for (int e = lo + (int)threadIdx.x; e < hi; e += 256) {
        const int s = src[e];
        const int p = atomicAdd(&cur[s >> LOCB], 1);
        pk[p] = ((s & 127) << 17) | dst[e];      // dst < 2^17
    }
}

// ---------------- finalize: per-bucket local CSR + edge weights ----------------
__global__ __launch_bounds__(256) void finalize_kernel(
    const int* __restrict__ pk, const int* __restrict__ bbase,
    const float* __restrict__ sl, const float* __restrict__ sr,
    int* __restrict__ off, int* __restrict__ bdst, __half* __restrict__ wgt,
    int n, int E)
{
    __shared__ int   lhist[128];
    __shared__ int   sc[256];
    __shared__ int   cur2[128];
    __shared__ float lsl[128];

    const int B  = blockIdx.x;
    const int b0 = bbase[B], b1 = bbase[B + 1];
    const int cnt = b1 - b0;
    const int t  = threadIdx.x;

    if (t < 128) {
        lhist[t] = 0;
        const int s = (B << LOCB) + t;
        lsl[t] = (s < n) ? sl[s] : 0.f;
    }
    __syncthreads();

    const int myn = (cnt > t) ? (cnt - t + 255) >> 8 : 0;
    int   pkr[MAXK];
    float wf[MAXK];
    #pragma unroll
    for (int k = 0; k < MAXK; k++) {
        if (k < myn) {
            const int v = pk[b0 + t + (k << 8)];
            pkr[k] = v;
            const int s = (v >> 17) & 127;
            atomicAdd(&lhist[s], 1);
            const float scv = lsl[s] + sr[v & 0x1FFFF];
            const float lr  = scv > 0.f ? scv : ALPHA * scv;
            wf[k] = __expf(-lr);
        }
    }
    for (int k = MAXK; k < myn; k++)
        atomicAdd(&lhist[(pk[b0 + t + (k << 8)] >> 17) & 127], 1);
    __syncthreads();

    const int v = (t < 128) ? lhist[t] : 0;
    sc[t] = v;
    __syncthreads();
    for (int d = 1; d < 256; d <<= 1) {
        int u = (t >= d) ? sc[t - d] : 0;
        __syncthreads();
        sc[t] += u;
        __syncthreads();
    }
    if (t < 128) {
        const int base = b0 + sc[t] - v;
        const int s = (B << LOCB) + t;
        if (s < n) off[s] = base;
        cur2[t] = base;
    }
    if (B == 0 && t == 0) off[n] = E;
    __syncthreads();

    #pragma unroll
    for (int k = 0; k < MAXK; k++) {
        if (k < myn) {
            const int w = pkr[k];
            const int p = atomicAdd(&cur2[(w >> 17) & 127], 1);
            bdst[p] = w & 0x1FFFF;
            wgt[p]  = __float2half(wf[k]);
        }
    }
    for (int k = MAXK; k < myn; k++) {
        const int w = pk[b0 + t + (k << 8)];
        const int s = (w >> 17) & 127, d = w & 0x1FFFF;
        const float scv = lsl[s] + sr[d];
        const float lr  = scv > 0.f ? scv : ALPHA * scv;
        const int p = atomicAdd(&cur2[s], 1);
        bdst[p] = d;
        wgt[p]  = __float2half(__expf(-lr));
    }
}

// ---- flat gather + LN + ELU: lane owns 4 features, wave does 4 edges/load ----
__global__ __launch_bounds__(256) void gather_kernel(
    const __half* __restrict__ hh,
    const int* __restrict__ off, const int* __restrict__ bdst,
    const __half* __restrict__ wgt,
    const float* __restrict__ gamma, const float* __restrict__ beta,
    float* __restrict__ out, int n)
{
    const int lane  = threadIdx.x & 63;
    const int fgrp  = lane & 15;
    const int equad = lane >> 4;
    const int wave  = (int)((blockIdx.x * blockDim.x + threadIdx.x) >> 6);
    const int nw    = (int)((gridDim.x * blockDim.x) >> 6);
    const float4 gm4 = ((const float4*)gamma)[fgrp];
    const float4 bt4 = ((const float4*)beta)[fgrp];

    for (int i = wave; i < n; i += nw) {
        const int o0 = off[i], o1 = off[i + 1];
        float4 acc = make_float4(0.f, 0.f, 0.f, 0.f);

        for (int base = o0; base < o1; base += 64) {
            const int j = base + lane;
            int d = 0; float w = 0.f;
            if (j < o1) { d = bdst[j]; w = __half2float(wgt[j]); }
            const int m = min(64, o1 - base);

            for (int t = 0; t < m; t += 8) {
                const int e0 = t + equad, e1 = t + 4 + equad;
                int   dd0 = __shfl(d, e0); float ww0 = __shfl(w, e0);
                int   dd1 = __shfl(d, e1); float ww1 = __shfl(w, e1);
                if (e0 >= m) { dd0 = 0; ww0 = 0.f; }
                if (e1 >= m) { dd1 = 0; ww1 = 0.f; }
                const uint2 u0 = ((const uint2*)hh)[(size_t)dd0 * 16 + fgrp];
                const uint2 u1 = ((const uint2*)hh)[(size_t)dd1 * 16 + fgrp];
                const float2 f00 = __half22float2(*(const __half2*)&u0.x);
                const float2 f01 = __half22float2(*(const __half2*)&u0.y);
                const float2 f10 = __half22float2(*(const __half2*)&u1.x);
                const float2 f11 = __half22float2(*(const __half2*)&u1.y);
                acc.x = fmaf(ww0, f00.x, acc.x); acc.y = fmaf(ww0, f00.y, acc.y);
                acc.z = fmaf(ww0, f01.x, acc.z); acc.w = fmaf(ww0, f01.y, acc.w);
                acc.x = fmaf(ww1, f10.x, acc.x); acc.y = fmaf(ww1, f10.y, acc.y);
                acc.z = fmaf(ww1, f11.x, acc.z); acc.w = fmaf(ww1, f11.y, acc.w);
            }
        }

        acc.x += __shfl_xor(acc.x, 16); acc.x += __shfl_xor(acc.x, 32);
        acc.y += __shfl_xor(acc.y, 16); acc.y += __shfl_xor(acc.y, 32);
        acc.z += __shfl_xor(acc.z, 16); acc.z += __shfl_xor(acc.z, 32);
        acc.w += __shfl_xor(acc.w, 16); acc.w += __shfl_xor(acc.w, 32);

        float s1 = acc.x + acc.y + acc.z + acc.w;
        #pragma unroll
        for (int dd = 1; dd < 16; dd <<= 1) s1 += __shfl_xor(s1, dd);
        const float mu = s1 * (1.f / 64.f);
        const float dx = acc.x - mu, dy = acc.y - mu, dz = acc.z - mu, dw = acc.w - mu;
        float s2 = dx * dx + dy * dy + dz * dz + dw * dw;
        #pragma unroll
        for (int dd = 1; dd < 16; dd <<= 1) s2 += __shfl_xor(s2, dd);
        const float rs = rsqrtf(s2 * (1.f / 64.f) + LN_EPS);

        float4 y;
        y.x = dx * rs * gm4.x + bt4.x;
        y.y = dy * rs * gm4.y + bt4.y;
        y.z = dz * rs * gm4.z + bt4.z;
        y.w = dw * rs * gm4.w + bt4.w;
        y.x = y.x > 0.f ? y.x : expm1f(y.x);
        y.y = y.y > 0.f ? y.y : expm1f(y.y);
        y.z = y.z > 0.f ? y.z : expm1f(y.z);
        y.w = y.w > 0.f ? y.w : expm1f(y.w);
        if (equad == 0)
            ((float4*)out)[(size_t)i * 16 + fgrp] = y;
    }
}

// ---------------- launch ----------------
extern "C" void kernel_launch(void* const* d_in, const int* in_sizes, int n_in,
                              void* d_out, int out_size, void* d_ws, size_t ws_size,
                              hipStream_t stream)
{
    const float* x     = (const float*)d_in[0];
    const int*   edge  = (const int*)  d_in[1];
    const float* W     = (const float*)d_in[2];
    const float* b     = (const float*)d_in[3];
    const float* a     = (const float*)d_in[4];
    const float* gamma = (const float*)d_in[5];
    const float* beta  = (const float*)d_in[6];
    float* out = (float*)d_out;

    const int n = in_sizes[0] / INF_;   // 100000
    const int E = in_sizes[1] / 2;      // 3200000
    const int* src = edge;
    const int* dst = edge + E;
    const int nbuck = (n + 127) >> 7;   // 782 buckets

    char* ws = (char*)d_ws;
    size_t offb = 0;
    auto alloc = [&](size_t bytes) -> void* {
        void* p = ws + offb;
        offb = (offb + bytes + 255) & ~(size_t)255;
        return p;
    };
    __half* hh    = (__half*)alloc((size_t)n * OUTF * 2);
    float*  sl    = (float*) alloc((size_t)n * 4);
    float*  sr    = (float*) alloc((size_t)n * 4);
    int*    M     = (int*)   alloc((size_t)NBLK * NB * 4);   // 8 MB
    int*    colsum= (int*)   alloc((size_t)NB * 4);
    int*    bbase = (int*)   alloc((size_t)(NB + 1) * 4);
    int*    off   = (int*)   alloc((size_t)(n + 1) * 4);
    int*    pk    = (int*)   alloc((size_t)E * 4);
    int*    bdst  = (int*)   alloc((size_t)E * 4);
    __half* wgt   = (__half*)alloc((size_t)E * 2);

    hipLaunchKernelGGL(count_coarse,    dim3(NBLK),   dim3(256),  0, stream, src, M, E);
    hipLaunchKernelGGL(colscan_kernel,  dim3(NB/256), dim3(256),  0, stream, M, colsum);
    hipLaunchKernelGGL(scan_bucket,     dim3(1),      dim3(1024), 0, stream, colsum, bbase);
    hipLaunchKernelGGL(scatter_coarse,  dim3(NBLK),   dim3(256),  0, stream, src, dst, M, bbase, pk, E);
    hipLaunchKernelGGL(gemm_kernel,     dim3(1024),   dim3(256),  0, stream, x, W, b, a, hh, sl, sr, n);
    hipLaunchKernelGGL(finalize_kernel, dim3(nbuck),  dim3(256),  0, stream, pk, bbase, sl, sr, off, bdst, wgt, n, E);
    hipLaunchKernelGGL(gather_kernel,   dim3(4096),   dim3(256),  0, stream, hh, off, bdst, wgt, gamma, beta, out, n);
}